// Round 1
// baseline (276.806 us; speedup 1.0000x reference)
//
#include <hip/hip_runtime.h>
#include <cmath>

// ---------------- helpers ----------------

static __device__ __forceinline__ float sigf(float v) {
    return 1.0f / (1.0f + expf(-v));
}

// Block (256 threads) sum-reduction in double. Valid result on thread 0.
static __device__ double block_reduce_sum(double v) {
    __shared__ double sh[4];
    for (int off = 32; off > 0; off >>= 1) v += __shfl_down(v, off, 64);
    int lane = threadIdx.x & 63, wid = threadIdx.x >> 6;
    if (lane == 0) sh[wid] = v;
    __syncthreads();
    v = (threadIdx.x < 4) ? sh[threadIdx.x] : 0.0;
    if (wid == 0) {
        v += __shfl_down(v, 2, 64);
        v += __shfl_down(v, 1, 64);
    }
    return v;
}

// ---------------- kernels ----------------

// init accumulators (ws is poisoned 0xAA before every timed launch)
__global__ void k_init(double* acc3, float* maxiou) {
    int id = blockIdx.x * blockDim.x + threadIdx.x;
    if (id < 3) acc3[id] = 0.0;
    if (id < 6400) maxiou[id] = 0.0f;
}

// negative-size penalty on RAW w/h: sum over 64*3*32*32 = 196608 cells
__global__ void k_negpen(const float* __restrict__ pred, double* __restrict__ neg_sum) {
    int id = blockIdx.x * 256 + threadIdx.x;  // grid covers exactly 196608
    const float* p = pred + (size_t)id * 5;
    float pw = p[2], ph = p[3];
    float s = fmaxf(1.0f - pw, 0.0f) + fmaxf(1.0f - ph, 0.0f);
    double v = block_reduce_sum((double)s);
    if (threadIdx.x == 0) atomicAdd(neg_sum, v);
}

// per-batch top-100 by conf (jax.lax.top_k semantics: desc value, ties -> lower idx),
// plus target box fixing and pred corner computation for selected boxes.
__global__ void k_topk(const float* __restrict__ pred, const float* __restrict__ tgt,
                       float* __restrict__ predc, float* __restrict__ targc,
                       float* __restrict__ confv) {
    const int b = blockIdx.x;   // 64 batches
    const int t = threadIdx.x;  // 256 threads

    // fix target boxes for this batch (epsilon = 1.0)
    if (t < 100) {
        int n = b * 100 + t;
        const float* tb = tgt + (size_t)n * 4;
        float a0 = tb[0], a1 = tb[1], a2 = tb[2], a3 = tb[3];
        float x1 = fminf(a0, a2), y1 = fminf(a1, a3);
        float x2 = fmaxf(a0, a2), y2 = fmaxf(a1, a3);
        if (x1 == x2) x2 = x1 + 1.0f;
        if (y1 == y2) y2 = y1 + 1.0f;
        targc[n * 4 + 0] = x1; targc[n * 4 + 1] = y1;
        targc[n * 4 + 2] = x2; targc[n * 4 + 3] = y2;
    }

    const float* pb = pred + (size_t)b * 3 * 32 * 32 * 5;

    // build keys: (conf bits << 32) | (0xFFFFFFFF - idx); conf > 0 so bits monotonic
    unsigned long long keys[12];
    unsigned long long lmax = 0ull;
    for (int r = 0; r < 12; ++r) {
        int idx = t + r * 256;  // [0, 3072)
        float c = sigf(pb[(size_t)idx * 5 + 4]);
        unsigned long long k = ((unsigned long long)__float_as_uint(c) << 32)
                             | (unsigned long long)(0xFFFFFFFFu - (unsigned)idx);
        keys[r] = k;
        lmax = lmax > k ? lmax : k;
    }

    __shared__ unsigned long long wmax[4];
    for (int k = 0; k < 100; ++k) {
        unsigned long long wm = lmax;
        for (int off = 32; off > 0; off >>= 1) {
            unsigned long long o = __shfl_down(wm, off, 64);
            wm = wm > o ? wm : o;
        }
        if ((t & 63) == 0) wmax[t >> 6] = wm;
        __syncthreads();
        unsigned long long gm = wmax[0];
        gm = gm > wmax[1] ? gm : wmax[1];
        gm = gm > wmax[2] ? gm : wmax[2];
        gm = gm > wmax[3] ? gm : wmax[3];
        if (lmax == gm) {  // unique owner (idx embedded in key)
            unsigned idx = 0xFFFFFFFFu - (unsigned)(gm & 0xFFFFFFFFull);
            float conf = __uint_as_float((unsigned)(gm >> 32));
            int n = b * 100 + k;
            confv[n] = conf;
            const float* pe = pb + (size_t)idx * 5;
            int w = idx & 31, h = (idx >> 5) & 31;  // flat = a*1024 + h*32 + w
            float x  = (sigf(pe[0]) + (float)w) * 32.0f;
            float y  = (sigf(pe[1]) + (float)h) * 32.0f;
            float bw = expf(pe[2]) * 32.0f;
            float bh = expf(pe[3]) * 32.0f;
            predc[n * 4 + 0] = x - bw * 0.5f;
            predc[n * 4 + 1] = y - bh * 0.5f;
            predc[n * 4 + 2] = x + bw * 0.5f;
            predc[n * 4 + 3] = y + bh * 0.5f;
            // remove winner, recompute local max
            lmax = 0ull;
            for (int r = 0; r < 12; ++r) {
                if (keys[r] == gm) keys[r] = 0ull;
                lmax = lmax > keys[r] ? lmax : keys[r];
            }
        }
        __syncthreads();
    }
}

// paired DIoU per n, plus smooth-L1 sum accumulation (25600 elements)
__global__ void k_diou(const float* __restrict__ predc, const float* __restrict__ targc,
                       float* __restrict__ diouv, double* __restrict__ sl1_sum) {
    int n = blockIdx.x * 256 + threadIdx.x;  // exactly 6400
    const float* p  = predc + (size_t)n * 4;
    const float* t4 = targc + (size_t)n * 4;
    float p0 = p[0], p1 = p[1], p2 = p[2], p3 = p[3];
    float t0 = t4[0], t1 = t4[1], t2 = t4[2], t3 = t4[3];
    float pa = fmaxf(p2 - p0, 0.f) * fmaxf(p3 - p1, 0.f);
    float ta = fmaxf(t2 - t0, 0.f) * fmaxf(t3 - t1, 0.f);
    float ix1 = fmaxf(p0, t0), iy1 = fmaxf(p1, t1);
    float ix2 = fminf(p2, t2), iy2 = fminf(p3, t3);
    float inter = fmaxf(ix2 - ix1, 0.f) * fmaxf(iy2 - iy1, 0.f);
    float iou = inter / (pa + ta - inter + 1e-7f);
    float pcx = (p0 + p2) * 0.5f, pcy = (p1 + p3) * 0.5f;
    float tcx = (t0 + t2) * 0.5f, tcy = (t1 + t3) * 0.5f;
    float cd = (pcx - tcx) * (pcx - tcx) + (pcy - tcy) * (pcy - tcy);
    float ex1 = fminf(p0, t0), ey1 = fminf(p1, t1);
    float ex2 = fmaxf(p2, t2), ey2 = fmaxf(p3, t3);
    float dg = (ex2 - ex1) * (ex2 - ex1) + (ey2 - ey1) * (ey2 - ey1);
    diouv[n] = 1.0f - (iou - cd / (dg + 1e-7f));
    double s = 0.0;
    #pragma unroll
    for (int c = 0; c < 4; ++c) {
        float d = p[c] - t4[c];
        float ad = fabsf(d);
        s += (double)(ad < 1.0f ? 0.5f * d * d : ad - 0.5f);
    }
    double v = block_reduce_sum(s);
    if (threadIdx.x == 0) atomicAdd(sl1_sum, v);
}

// max over ALL 6400 preds of IoU(pred_i, target_j), per target j.
// grid (25, 16): 256 targets per block.x, 400 preds per block.y chunk.
__global__ void k_maxiou(const float* __restrict__ predc, const float* __restrict__ targc,
                         unsigned int* __restrict__ maxiou_bits) {
    __shared__ float4 pl[400];
    int t = threadIdx.x;
    int j = blockIdx.x * 256 + t;
    const float4* pc4 = (const float4*)predc;
    int i0 = blockIdx.y * 400;
    for (int i = t; i < 400; i += 256) pl[i] = pc4[i0 + i];
    float4 tj = ((const float4*)targc)[j];
    float ta = (tj.z - tj.x) * (tj.w - tj.y);
    __syncthreads();
    float m = 0.0f;
    for (int i = 0; i < 400; ++i) {
        float4 p = pl[i];
        float pa = (p.z - p.x) * (p.w - p.y);
        float w = fminf(p.z, tj.z) - fmaxf(p.x, tj.x); w = fmaxf(w, 0.f);
        float h = fminf(p.w, tj.w) - fmaxf(p.y, tj.y); h = fmaxf(h, 0.f);
        float inter = w * h;
        float iou = inter / (pa + ta - inter);  // _box_iou has no eps
        m = fmaxf(m, iou);                      // fmaxf drops NaN => nan_to_num+clip
    }
    // IoU >= 0, so uint bit-pattern compare == float compare
    atomicMax(&maxiou_bits[j], __float_as_uint(m));
}

// sum over the [N,N] broadcast of good - bad.
// grid (25 j-blocks, 25 i-chunks); thread owns x[j], loops 256 y[i] from LDS.
__global__ void k_pair(const unsigned int* __restrict__ maxiou_bits,
                       const float* __restrict__ diouv,
                       const float* __restrict__ confv,
                       const double* __restrict__ sl1_sum,
                       double* __restrict__ pair_sum) {
    __shared__ float ys[256];
    int t = threadIdx.x;
    int j = blockIdx.x * 256 + t;
    float sl1 = (float)((*sl1_sum) / 25600.0 / 512.0);
    float xj = (1.0f - __uint_as_float(maxiou_bits[j])) * 2.0f + diouv[j] + sl1;
    int i0 = blockIdx.y * 256;
    ys[t] = confv[i0 + t];
    __syncthreads();
    float a2 = xj * xj;
    float bb = 3.5f - xj;
    float b2 = bb * bb;
    float acc = 0.0f;
    for (int i = 0; i < 256; ++i) {
        float oy = 1.0f - ys[i];
        float oy2 = oy * oy;
        acc += 2.0f * sqrtf(a2 + oy2) - 1.5f * sqrtf(b2 + oy2);
    }
    double v = block_reduce_sum((double)acc);
    if (t == 0) atomicAdd(pair_sum, v);
}

__global__ void k_final(const double* __restrict__ pair_sum,
                        const double* __restrict__ neg_sum,
                        float* __restrict__ out) {
    double mean_pair = *pair_sum / 40960000.0;           // 6400*6400
    float losses = fmaxf((float)mean_pair + 5.25f, 0.0f); // + max_loss*BAD_MULT
    float neg = (float)(*neg_sum / 196608.0);
    out[0] = losses + neg;
}

// ---------------- launch ----------------

extern "C" void kernel_launch(void* const* d_in, const int* in_sizes, int n_in,
                              void* d_out, int out_size, void* d_ws, size_t ws_size,
                              hipStream_t stream) {
    const float* pred = (const float*)d_in[0];   // [64,3,32,32,5]
    const float* tgt  = (const float*)d_in[1];   // [64,100,4]
    float* out = (float*)d_out;

    char* ws = (char*)d_ws;
    double* acc3     = (double*)ws;              // [neg_sum, sl1_sum, pair_sum]
    double* neg_sum  = acc3 + 0;
    double* sl1_sum  = acc3 + 1;
    double* pair_sum = acc3 + 2;
    float* fbase   = (float*)(ws + 64);
    float* predc   = fbase;            // 25600 floats
    float* targc   = fbase + 25600;    // 25600 floats
    float* confv   = fbase + 51200;    // 6400 floats
    float* diouv   = fbase + 57600;    // 6400 floats
    float* maxiou  = fbase + 64000;    // 6400 floats
    unsigned int* maxiou_bits = (unsigned int*)maxiou;

    k_init<<<25, 256, 0, stream>>>(acc3, maxiou);
    k_negpen<<<768, 256, 0, stream>>>(pred, neg_sum);
    k_topk<<<64, 256, 0, stream>>>(pred, tgt, predc, targc, confv);
    k_diou<<<25, 256, 0, stream>>>(predc, targc, diouv, sl1_sum);
    k_maxiou<<<dim3(25, 16), 256, 0, stream>>>(predc, targc, maxiou_bits);
    k_pair<<<dim3(25, 25), 256, 0, stream>>>(maxiou_bits, diouv, confv, sl1_sum, pair_sum);
    k_final<<<1, 1, 0, stream>>>(pair_sum, neg_sum, out);
}

// Round 2
// 180.843 us; speedup vs baseline: 1.5306x; 1.5306x over previous
//
#include <hip/hip_runtime.h>
#include <cmath>

#define NKEY 3072
#define KSEL 100

static __device__ __forceinline__ float sigf(float v) {
    return 1.0f / (1.0f + expf(-v));
}

// Block (256 threads) sum-reduction in double. Valid result on thread 0.
// Leading barrier makes back-to-back calls safe.
static __device__ double block_reduce_sum(double v) {
    __shared__ double sh[4];
    __syncthreads();
    for (int off = 32; off > 0; off >>= 1) v += __shfl_down(v, off, 64);
    int lane = threadIdx.x & 63, wid = threadIdx.x >> 6;
    if (lane == 0) sh[wid] = v;
    __syncthreads();
    v = (threadIdx.x < 4) ? sh[threadIdx.x] : 0.0;
    if (wid == 0) {
        v += __shfl_down(v, 2, 64);
        v += __shfl_down(v, 1, 64);
    }
    return v;
}

// ---------------------------------------------------------------------------
// k_topk: per-batch (64 blocks) --
//   * build u64 keys (conf_bits<<32 | ~idx) for 3072 cells, accumulate
//     negative-size penalty partial (fused: same cache lines)
//   * radix-select the exact 100th-largest key (jax.lax.top_k semantics:
//     descending value, ties -> lower index; key packing encodes this)
//   * compact the 100 selected keys, rank by counting, write pred corners /
//     conf in sorted order; fix target boxes; zero maxiou_bits slice
// ---------------------------------------------------------------------------
__global__ __launch_bounds__(256) void k_topk(const float* __restrict__ pred,
                                              const float* __restrict__ tgt,
                                              float* __restrict__ predc,
                                              float* __restrict__ targc,
                                              float* __restrict__ confv,
                                              unsigned int* __restrict__ maxiou_bits,
                                              double* __restrict__ negp /*[64]*/) {
    const int b = blockIdx.x;
    const int t = threadIdx.x;

    __shared__ unsigned long long keys[NKEY];   // 24 KB
    __shared__ unsigned int hist[256];
    __shared__ unsigned long long sel[KSEL];
    __shared__ unsigned long long tkey_sh;
    __shared__ unsigned int scnt;
    __shared__ int bdigit_sh;
    __shared__ int bk_sh;

    // ---- target box fixing (epsilon = 1.0) + maxiou init ----
    if (t < KSEL) {
        int n = b * KSEL + t;
        const float* tb = tgt + (size_t)n * 4;
        float a0 = tb[0], a1 = tb[1], a2 = tb[2], a3 = tb[3];
        float x1 = fminf(a0, a2), y1 = fminf(a1, a3);
        float x2 = fmaxf(a0, a2), y2 = fmaxf(a1, a3);
        if (x1 == x2) x2 = x1 + 1.0f;
        if (y1 == y2) y2 = y1 + 1.0f;
        targc[n * 4 + 0] = x1; targc[n * 4 + 1] = y1;
        targc[n * 4 + 2] = x2; targc[n * 4 + 3] = y2;
        maxiou_bits[n] = 0u;
    }
    if (t == 0) scnt = 0;

    // ---- phase A: keys + negpen partial ----
    const float* pb = pred + (size_t)b * (NKEY * 5);
    float negacc = 0.0f;
    for (int r = 0; r < 12; ++r) {
        int idx = t + r * 256;
        const float* pe = pb + (size_t)idx * 5;
        float w = pe[2], h = pe[3], cl = pe[4];
        negacc += fmaxf(1.0f - w, 0.0f) + fmaxf(1.0f - h, 0.0f);
        float c = sigf(cl);
        keys[idx] = ((unsigned long long)__float_as_uint(c) << 32)
                  | (unsigned long long)(0xFFFFFFFFu - (unsigned)idx);
    }
    {
        double v = block_reduce_sum((double)negacc);  // has its own barriers
        if (t == 0) negp[b] = v;
    }
    __syncthreads();  // keys + scnt visible

    // ---- phase B: radix select (MSB-first 8-bit digits) ----
    unsigned long long prefix = 0ull;
    int plen = 0;       // matched high bits
    int k = KSEL;       // rank within prefix-matched subset
    bool done = false;
    for (int round = 0; round < 8 && !done; ++round) {
        hist[t] = 0u;
        __syncthreads();
        int shift = 56 - 8 * round;
        for (int r = 0; r < 12; ++r) {
            unsigned long long key = keys[t + r * 256];
            if (plen == 0 || (key >> (64 - plen)) == (prefix >> (64 - plen))) {
                atomicAdd(&hist[(unsigned)((key >> shift) & 0xFFull)], 1u);
            }
        }
        __syncthreads();
        if (t < 64) {  // wave 0: suffix-scan the 256-bin histogram
            unsigned s0 = hist[4 * t + 0], s1 = hist[4 * t + 1];
            unsigned s2 = hist[4 * t + 2], s3 = hist[4 * t + 3];
            unsigned ssum = s0 + s1 + s2 + s3;
            unsigned suf = ssum;  // inclusive suffix sum across lanes
            for (int off = 1; off < 64; off <<= 1) {
                unsigned o = __shfl_down(suf, off, 64);
                if (t + off < 64) suf += o;
            }
            unsigned above = suf - ssum;  // keys with digit >= 4(t+1)
            if (above < (unsigned)k && suf >= (unsigned)k) {
                unsigned hh[4] = {s0, s1, s2, s3};
                unsigned cum = above;
                for (int q = 3; q >= 0; --q) {
                    unsigned c = hh[q];
                    if (cum + c >= (unsigned)k) { bdigit_sh = 4 * t + q; bk_sh = k - (int)cum; break; }
                    cum += c;
                }
            }
        }
        __syncthreads();
        int d = bdigit_sh;
        k = bk_sh;
        prefix |= ((unsigned long long)(unsigned)d) << shift;
        plen += 8;
        unsigned ceq = hist[d];
        if (ceq == 1u) {  // unique bucket: the 100th key is determined
            for (int r = 0; r < 12; ++r) {
                unsigned long long key = keys[t + r * 256];
                if ((key >> (64 - plen)) == (prefix >> (64 - plen))) tkey_sh = key;
            }
            done = true;  // uniform (ceq is uniform)
        }
        __syncthreads();
    }
    // round 7 examines the full key (all keys unique) => tkey_sh always set
    unsigned long long T = tkey_sh;

    // ---- phase C: compact + rank + emit ----
    for (int r = 0; r < 12; ++r) {
        unsigned long long key = keys[t + r * 256];
        if (key >= T) {
            unsigned pos = atomicAdd(&scnt, 1u);  // exactly 100 total
            sel[pos] = key;
        }
    }
    __syncthreads();
    if (t < KSEL) {
        unsigned long long key = sel[t];
        int rank = 0;
        for (int p = 0; p < KSEL; ++p) rank += (sel[p] > key) ? 1 : 0;
        unsigned idx = 0xFFFFFFFFu - (unsigned)(key & 0xFFFFFFFFull);
        float conf = __uint_as_float((unsigned)(key >> 32));
        int n = b * KSEL + rank;
        confv[n] = conf;
        const float* pe = pb + (size_t)idx * 5;
        int w = idx & 31, h = (idx >> 5) & 31;  // flat = a*1024 + h*32 + w
        float x  = (sigf(pe[0]) + (float)w) * 32.0f;
        float y  = (sigf(pe[1]) + (float)h) * 32.0f;
        float bw = expf(pe[2]) * 32.0f;
        float bh = expf(pe[3]) * 32.0f;
        predc[n * 4 + 0] = x - bw * 0.5f;
        predc[n * 4 + 1] = y - bh * 0.5f;
        predc[n * 4 + 2] = x + bw * 0.5f;
        predc[n * 4 + 3] = y + bh * 0.5f;
    }
}

// ---------------------------------------------------------------------------
// k_maxiou: grid (25, 16). block (x, y): targets j in [x*256, x*256+256),
// preds i in [y*400, y*400+400) staged in LDS; atomicMax (float-as-uint, IoU>=0).
// blockIdx.y == 0 additionally computes paired DIoU and the smooth-L1 partial.
// ---------------------------------------------------------------------------
__global__ __launch_bounds__(256) void k_maxiou(const float* __restrict__ predc,
                                                const float* __restrict__ targc,
                                                unsigned int* __restrict__ maxiou_bits,
                                                float* __restrict__ diouv,
                                                double* __restrict__ sl1p /*[25]*/) {
    __shared__ float4 pl[400];
    int t = threadIdx.x;
    int j = blockIdx.x * 256 + t;
    const float4* pc4 = (const float4*)predc;
    int i0 = blockIdx.y * 400;
    for (int i = t; i < 400; i += 256) pl[i] = pc4[i0 + i];
    float4 tj = ((const float4*)targc)[j];
    float ta = (tj.z - tj.x) * (tj.w - tj.y);
    __syncthreads();
    float m = 0.0f;
    for (int i = 0; i < 400; ++i) {
        float4 p = pl[i];
        float pa = (p.z - p.x) * (p.w - p.y);
        float w = fminf(p.z, tj.z) - fmaxf(p.x, tj.x); w = fmaxf(w, 0.0f);
        float h = fminf(p.w, tj.w) - fmaxf(p.y, tj.y); h = fmaxf(h, 0.0f);
        float inter = w * h;
        float iou = inter / (pa + ta - inter);  // _box_iou: no eps
        m = fmaxf(m, iou);                      // drops NaN, clips >= 0 (init 0)
    }
    atomicMax(&maxiou_bits[j], __float_as_uint(m));

    if (blockIdx.y == 0) {
        float4 p = pc4[j];  // paired pred for target j
        float pa = fmaxf(p.z - p.x, 0.f) * fmaxf(p.w - p.y, 0.f);
        float ta2 = fmaxf(tj.z - tj.x, 0.f) * fmaxf(tj.w - tj.y, 0.f);
        float ix1 = fmaxf(p.x, tj.x), iy1 = fmaxf(p.y, tj.y);
        float ix2 = fminf(p.z, tj.z), iy2 = fminf(p.w, tj.w);
        float inter = fmaxf(ix2 - ix1, 0.f) * fmaxf(iy2 - iy1, 0.f);
        float iou = inter / (pa + ta2 - inter + 1e-7f);
        float pcx = (p.x + p.z) * 0.5f, pcy = (p.y + p.w) * 0.5f;
        float tcx = (tj.x + tj.z) * 0.5f, tcy = (tj.y + tj.w) * 0.5f;
        float cd = (pcx - tcx) * (pcx - tcx) + (pcy - tcy) * (pcy - tcy);
        float ex1 = fminf(p.x, tj.x), ey1 = fminf(p.y, tj.y);
        float ex2 = fmaxf(p.z, tj.z), ey2 = fmaxf(p.w, tj.w);
        float dg = (ex2 - ex1) * (ex2 - ex1) + (ey2 - ey1) * (ey2 - ey1);
        diouv[j] = 1.0f - (iou - cd / (dg + 1e-7f));
        double s = 0.0;
        {
            float d0 = p.x - tj.x, d1 = p.y - tj.y, d2 = p.z - tj.z, d3 = p.w - tj.w;
            float a0 = fabsf(d0), a1 = fabsf(d1), a2 = fabsf(d2), a3 = fabsf(d3);
            s += (double)(a0 < 1.f ? 0.5f * d0 * d0 : a0 - 0.5f);
            s += (double)(a1 < 1.f ? 0.5f * d1 * d1 : a1 - 0.5f);
            s += (double)(a2 < 1.f ? 0.5f * d2 * d2 : a2 - 0.5f);
            s += (double)(a3 < 1.f ? 0.5f * d3 * d3 : a3 - 0.5f);
        }
        double v = block_reduce_sum(s);
        if (t == 0) sl1p[blockIdx.x] = v;
    }
}

// ---------------------------------------------------------------------------
// k_pair: sum over the [N,N] broadcast of good - bad. grid (25 j, 25 i).
// Writes one double partial per block (no atomics).
// ---------------------------------------------------------------------------
__global__ __launch_bounds__(256) void k_pair(const unsigned int* __restrict__ maxiou_bits,
                                              const float* __restrict__ diouv,
                                              const float* __restrict__ confv,
                                              const double* __restrict__ sl1p,
                                              double* __restrict__ pairp /*[625]*/) {
    __shared__ float ys[256];
    __shared__ float sl1_sh;
    int t = threadIdx.x;
    int j = blockIdx.x * 256 + t;
    if (t == 0) {
        double s = 0.0;
        for (int i = 0; i < 25; ++i) s += sl1p[i];
        sl1_sh = (float)(s / 25600.0 / 512.0);
    }
    ys[t] = confv[blockIdx.y * 256 + t];
    float mj = __uint_as_float(maxiou_bits[j]);
    float dj = diouv[j];
    __syncthreads();
    float xj = (1.0f - mj) * 2.0f + dj + sl1_sh;
    float a2 = xj * xj;
    float bb = 3.5f - xj;
    float b2 = bb * bb;
    float acc = 0.0f;
    for (int i = 0; i < 256; ++i) {
        float oy = 1.0f - ys[i];
        float oy2 = oy * oy;
        acc += 2.0f * sqrtf(a2 + oy2) - 1.5f * sqrtf(b2 + oy2);
    }
    double v = block_reduce_sum((double)acc);
    if (t == 0) pairp[blockIdx.x * 25 + blockIdx.y] = v;
}

// ---------------------------------------------------------------------------
// k_final: reduce 625 pair partials + 64 negpen partials, emit scalar.
// ---------------------------------------------------------------------------
__global__ __launch_bounds__(256) void k_final(const double* __restrict__ pairp,
                                               const double* __restrict__ negp,
                                               float* __restrict__ out) {
    int t = threadIdx.x;
    double s = 0.0;
    for (int i = t; i < 625; i += 256) s += pairp[i];
    double ps = block_reduce_sum(s);
    double n = (t < 64) ? negp[t] : 0.0;
    double ns = block_reduce_sum(n);
    if (t == 0) {
        double mean_pair = ps / 40960000.0;                    // 6400*6400
        float losses = fmaxf((float)mean_pair + 5.25f, 0.0f);  // + 3.5*1.5
        float neg = (float)(ns / 196608.0);
        out[0] = losses + neg;
    }
}

// ---------------- launch ----------------

extern "C" void kernel_launch(void* const* d_in, const int* in_sizes, int n_in,
                              void* d_out, int out_size, void* d_ws, size_t ws_size,
                              hipStream_t stream) {
    const float* pred = (const float*)d_in[0];   // [64,3,32,32,5]
    const float* tgt  = (const float*)d_in[1];   // [64,100,4]
    float* out = (float*)d_out;

    char* ws = (char*)d_ws;
    double* negp  = (double*)ws;             // 64 doubles
    double* sl1p  = negp + 64;               // 25 (padded to 32)
    double* pairp = negp + 96;               // 625 doubles -> ends at 721*8 = 5768
    float* fbase  = (float*)(ws + 6400);     // 16B-aligned float region
    float* predc  = fbase;                   // 25600 floats
    float* targc  = fbase + 25600;           // 25600
    float* confv  = fbase + 51200;           // 6400
    float* diouv  = fbase + 57600;           // 6400
    unsigned int* maxiou_bits = (unsigned int*)(fbase + 64000);  // 6400

    k_topk<<<64, 256, 0, stream>>>(pred, tgt, predc, targc, confv, maxiou_bits, negp);
    k_maxiou<<<dim3(25, 16), 256, 0, stream>>>(predc, targc, maxiou_bits, diouv, sl1p);
    k_pair<<<dim3(25, 25), 256, 0, stream>>>(maxiou_bits, diouv, confv, sl1p, pairp);
    k_final<<<1, 256, 0, stream>>>(pairp, negp, out);
}

// Round 3
// 107.786 us; speedup vs baseline: 2.5681x; 1.6778x over previous
//
#include <hip/hip_runtime.h>
#include <cmath>

#define NKEY 3072
#define KSEL 100
#define PCHUNK 200   // preds per k_maxiou block; grid.y = 6400/PCHUNK = 32

static __device__ __forceinline__ float sigf(float v) {
    return 1.0f / (1.0f + expf(-v));
}

// Block (256 threads) sum-reduction in double. Valid result on thread 0.
// Leading barrier makes back-to-back calls safe.
static __device__ double block_reduce_sum(double v) {
    __shared__ double sh[4];
    __syncthreads();
    for (int off = 32; off > 0; off >>= 1) v += __shfl_down(v, off, 64);
    int lane = threadIdx.x & 63, wid = threadIdx.x >> 6;
    if (lane == 0) sh[wid] = v;
    __syncthreads();
    v = (threadIdx.x < 4) ? sh[threadIdx.x] : 0.0;
    if (wid == 0) {
        v += __shfl_down(v, 2, 64);
        v += __shfl_down(v, 1, 64);
    }
    return v;
}

// ---------------------------------------------------------------------------
// k_topk: per-batch (64 blocks) --
//   * build u64 keys (conf_bits<<32 | ~idx) for 3072 cells, accumulate
//     negative-size penalty partial (fused: same cache lines)
//   * radix-select the exact 100th-largest key (jax.lax.top_k semantics:
//     descending value, ties -> lower index; key packing encodes this)
//   * compact the 100 selected keys, rank by counting, write pred corners /
//     conf in sorted order; fix target boxes; zero maxiou_bits slice
// ---------------------------------------------------------------------------
__global__ __launch_bounds__(256) void k_topk(const float* __restrict__ pred,
                                              const float* __restrict__ tgt,
                                              float* __restrict__ predc,
                                              float* __restrict__ targc,
                                              float* __restrict__ confv,
                                              unsigned int* __restrict__ maxiou_bits,
                                              double* __restrict__ negp /*[64]*/) {
    const int b = blockIdx.x;
    const int t = threadIdx.x;

    __shared__ unsigned long long keys[NKEY];   // 24 KB
    __shared__ unsigned int hist[256];
    __shared__ unsigned long long sel[KSEL];
    __shared__ unsigned long long tkey_sh;
    __shared__ unsigned int scnt;
    __shared__ int bdigit_sh;
    __shared__ int bk_sh;

    // ---- target box fixing (epsilon = 1.0) + maxiou init ----
    if (t < KSEL) {
        int n = b * KSEL + t;
        const float* tb = tgt + (size_t)n * 4;
        float a0 = tb[0], a1 = tb[1], a2 = tb[2], a3 = tb[3];
        float x1 = fminf(a0, a2), y1 = fminf(a1, a3);
        float x2 = fmaxf(a0, a2), y2 = fmaxf(a1, a3);
        if (x1 == x2) x2 = x1 + 1.0f;
        if (y1 == y2) y2 = y1 + 1.0f;
        targc[n * 4 + 0] = x1; targc[n * 4 + 1] = y1;
        targc[n * 4 + 2] = x2; targc[n * 4 + 3] = y2;
        maxiou_bits[n] = 0u;
    }
    if (t == 0) scnt = 0;

    // ---- phase A: keys + negpen partial ----
    const float* pb = pred + (size_t)b * (NKEY * 5);
    float negacc = 0.0f;
    for (int r = 0; r < 12; ++r) {
        int idx = t + r * 256;
        const float* pe = pb + (size_t)idx * 5;
        float w = pe[2], h = pe[3], cl = pe[4];
        negacc += fmaxf(1.0f - w, 0.0f) + fmaxf(1.0f - h, 0.0f);
        float c = sigf(cl);
        keys[idx] = ((unsigned long long)__float_as_uint(c) << 32)
                  | (unsigned long long)(0xFFFFFFFFu - (unsigned)idx);
    }
    {
        double v = block_reduce_sum((double)negacc);  // has its own barriers
        if (t == 0) negp[b] = v;
    }
    __syncthreads();  // keys + scnt visible

    // ---- phase B: radix select (MSB-first 8-bit digits) ----
    unsigned long long prefix = 0ull;
    int plen = 0;       // matched high bits
    int k = KSEL;       // rank within prefix-matched subset
    bool done = false;
    for (int round = 0; round < 8 && !done; ++round) {
        hist[t] = 0u;
        __syncthreads();
        int shift = 56 - 8 * round;
        for (int r = 0; r < 12; ++r) {
            unsigned long long key = keys[t + r * 256];
            if (plen == 0 || (key >> (64 - plen)) == (prefix >> (64 - plen))) {
                atomicAdd(&hist[(unsigned)((key >> shift) & 0xFFull)], 1u);
            }
        }
        __syncthreads();
        if (t < 64) {  // wave 0: suffix-scan the 256-bin histogram
            unsigned s0 = hist[4 * t + 0], s1 = hist[4 * t + 1];
            unsigned s2 = hist[4 * t + 2], s3 = hist[4 * t + 3];
            unsigned ssum = s0 + s1 + s2 + s3;
            unsigned suf = ssum;  // inclusive suffix sum across lanes
            for (int off = 1; off < 64; off <<= 1) {
                unsigned o = __shfl_down(suf, off, 64);
                if (t + off < 64) suf += o;
            }
            unsigned above = suf - ssum;  // keys with digit >= 4(t+1)
            if (above < (unsigned)k && suf >= (unsigned)k) {
                unsigned hh[4] = {s0, s1, s2, s3};
                unsigned cum = above;
                for (int q = 3; q >= 0; --q) {
                    unsigned c = hh[q];
                    if (cum + c >= (unsigned)k) { bdigit_sh = 4 * t + q; bk_sh = k - (int)cum; break; }
                    cum += c;
                }
            }
        }
        __syncthreads();
        int d = bdigit_sh;
        k = bk_sh;
        prefix |= ((unsigned long long)(unsigned)d) << shift;
        plen += 8;
        unsigned ceq = hist[d];
        if (ceq == 1u) {  // unique bucket: the 100th key is determined
            for (int r = 0; r < 12; ++r) {
                unsigned long long key = keys[t + r * 256];
                if ((key >> (64 - plen)) == (prefix >> (64 - plen))) tkey_sh = key;
            }
            done = true;  // uniform (ceq is uniform)
        }
        __syncthreads();
    }
    // round 7 examines the full key (all keys unique) => tkey_sh always set
    unsigned long long T = tkey_sh;

    // ---- phase C: compact + rank + emit ----
    for (int r = 0; r < 12; ++r) {
        unsigned long long key = keys[t + r * 256];
        if (key >= T) {
            unsigned pos = atomicAdd(&scnt, 1u);  // exactly 100 total
            sel[pos] = key;
        }
    }
    __syncthreads();
    if (t < KSEL) {
        unsigned long long key = sel[t];
        int rank = 0;
        for (int p = 0; p < KSEL; ++p) rank += (sel[p] > key) ? 1 : 0;
        unsigned idx = 0xFFFFFFFFu - (unsigned)(key & 0xFFFFFFFFull);
        float conf = __uint_as_float((unsigned)(key >> 32));
        int n = b * KSEL + rank;
        confv[n] = conf;
        const float* pe = pb + (size_t)idx * 5;
        int w = idx & 31, h = (idx >> 5) & 31;  // flat = a*1024 + h*32 + w
        float x  = (sigf(pe[0]) + (float)w) * 32.0f;
        float y  = (sigf(pe[1]) + (float)h) * 32.0f;
        float bw = expf(pe[2]) * 32.0f;
        float bh = expf(pe[3]) * 32.0f;
        predc[n * 4 + 0] = x - bw * 0.5f;
        predc[n * 4 + 1] = y - bh * 0.5f;
        predc[n * 4 + 2] = x + bw * 0.5f;
        predc[n * 4 + 3] = y + bh * 0.5f;
    }
}

// ---------------------------------------------------------------------------
// k_maxiou: grid (25, 32). block (x, y): targets j in [x*256, x*256+256),
// preds i in [y*200, y*200+200) staged in LDS (boxes + precomputed areas);
// atomicMax (float-as-uint, IoU >= 0). iou via v_rcp_f32: union > 0 strictly
// here (pred areas are exp-products > 0; target boxes epsilon-fixed), ~1 ulp.
// blockIdx.y == 0 additionally computes paired DIoU and the smooth-L1 partial.
// ---------------------------------------------------------------------------
__global__ __launch_bounds__(256) void k_maxiou(const float* __restrict__ predc,
                                                const float* __restrict__ targc,
                                                unsigned int* __restrict__ maxiou_bits,
                                                float* __restrict__ diouv,
                                                double* __restrict__ sl1p /*[25]*/) {
    __shared__ float4 pl[PCHUNK];
    __shared__ float pa_sh[PCHUNK];
    int t = threadIdx.x;
    int j = blockIdx.x * 256 + t;
    const float4* pc4 = (const float4*)predc;
    int i0 = blockIdx.y * PCHUNK;
    for (int i = t; i < PCHUNK; i += 256) {
        float4 p = pc4[i0 + i];
        pl[i] = p;
        pa_sh[i] = (p.z - p.x) * (p.w - p.y);
    }
    float4 tj = ((const float4*)targc)[j];
    float ta = (tj.z - tj.x) * (tj.w - tj.y);
    __syncthreads();
    float m0 = 0.0f, m1 = 0.0f;
    #pragma unroll 2
    for (int i = 0; i < PCHUNK; i += 2) {
        float4 p = pl[i];
        float w0 = fmaxf(fminf(p.z, tj.z) - fmaxf(p.x, tj.x), 0.0f);
        float h0 = fmaxf(fminf(p.w, tj.w) - fmaxf(p.y, tj.y), 0.0f);
        float in0 = w0 * h0;
        float iou0 = in0 * __builtin_amdgcn_rcpf(pa_sh[i] + ta - in0);
        m0 = fmaxf(m0, iou0);
        float4 q = pl[i + 1];
        float w1 = fmaxf(fminf(q.z, tj.z) - fmaxf(q.x, tj.x), 0.0f);
        float h1 = fmaxf(fminf(q.w, tj.w) - fmaxf(q.y, tj.y), 0.0f);
        float in1 = w1 * h1;
        float iou1 = in1 * __builtin_amdgcn_rcpf(pa_sh[i + 1] + ta - in1);
        m1 = fmaxf(m1, iou1);
    }
    m0 = fmaxf(m0, m1);
    atomicMax(&maxiou_bits[j], __float_as_uint(m0));

    if (blockIdx.y == 0) {
        float4 p = pc4[j];  // paired pred for target j
        float pa = fmaxf(p.z - p.x, 0.f) * fmaxf(p.w - p.y, 0.f);
        float ta2 = fmaxf(tj.z - tj.x, 0.f) * fmaxf(tj.w - tj.y, 0.f);
        float ix1 = fmaxf(p.x, tj.x), iy1 = fmaxf(p.y, tj.y);
        float ix2 = fminf(p.z, tj.z), iy2 = fminf(p.w, tj.w);
        float inter = fmaxf(ix2 - ix1, 0.f) * fmaxf(iy2 - iy1, 0.f);
        float iou = inter / (pa + ta2 - inter + 1e-7f);
        float pcx = (p.x + p.z) * 0.5f, pcy = (p.y + p.w) * 0.5f;
        float tcx = (tj.x + tj.z) * 0.5f, tcy = (tj.y + tj.w) * 0.5f;
        float cd = (pcx - tcx) * (pcx - tcx) + (pcy - tcy) * (pcy - tcy);
        float ex1 = fminf(p.x, tj.x), ey1 = fminf(p.y, tj.y);
        float ex2 = fmaxf(p.z, tj.z), ey2 = fmaxf(p.w, tj.w);
        float dg = (ex2 - ex1) * (ex2 - ex1) + (ey2 - ey1) * (ey2 - ey1);
        diouv[j] = 1.0f - (iou - cd / (dg + 1e-7f));
        double s = 0.0;
        {
            float d0 = p.x - tj.x, d1 = p.y - tj.y, d2 = p.z - tj.z, d3 = p.w - tj.w;
            float a0 = fabsf(d0), a1 = fabsf(d1), a2 = fabsf(d2), a3 = fabsf(d3);
            s += (double)(a0 < 1.f ? 0.5f * d0 * d0 : a0 - 0.5f);
            s += (double)(a1 < 1.f ? 0.5f * d1 * d1 : a1 - 0.5f);
            s += (double)(a2 < 1.f ? 0.5f * d2 * d2 : a2 - 0.5f);
            s += (double)(a3 < 1.f ? 0.5f * d3 * d3 : a3 - 0.5f);
        }
        double v = block_reduce_sum(s);
        if (t == 0) sl1p[blockIdx.x] = v;
    }
}

// ---------------------------------------------------------------------------
// k_pair: sum over the [N,N] broadcast of good - bad. grid (25 j, 25 i).
// (1-y)^2 precomputed in LDS; raw v_sqrt_f32 (~1 ulp vs 0.28 threshold).
// Writes one double partial per block (no atomics).
// ---------------------------------------------------------------------------
__global__ __launch_bounds__(256) void k_pair(const unsigned int* __restrict__ maxiou_bits,
                                              const float* __restrict__ diouv,
                                              const float* __restrict__ confv,
                                              const double* __restrict__ sl1p,
                                              double* __restrict__ pairp /*[625]*/) {
    __shared__ float oy2s[256];
    __shared__ float sl1_sh;
    int t = threadIdx.x;
    int j = blockIdx.x * 256 + t;
    if (t == 0) {
        double s = 0.0;
        for (int i = 0; i < 25; ++i) s += sl1p[i];
        sl1_sh = (float)(s / 25600.0 / 512.0);
    }
    {
        float oy = 1.0f - confv[blockIdx.y * 256 + t];
        oy2s[t] = oy * oy;
    }
    float mj = __uint_as_float(maxiou_bits[j]);
    float dj = diouv[j];
    __syncthreads();
    float xj = (1.0f - mj) * 2.0f + dj + sl1_sh;
    float a2 = xj * xj;
    float bb = 3.5f - xj;
    float b2 = bb * bb;
    float acc0 = 0.0f, acc1 = 0.0f;
    #pragma unroll 4
    for (int i = 0; i < 256; i += 2) {
        float o0 = oy2s[i], o1 = oy2s[i + 1];
        acc0 += 2.0f * __builtin_amdgcn_sqrtf(a2 + o0)
              - 1.5f * __builtin_amdgcn_sqrtf(b2 + o0);
        acc1 += 2.0f * __builtin_amdgcn_sqrtf(a2 + o1)
              - 1.5f * __builtin_amdgcn_sqrtf(b2 + o1);
    }
    double v = block_reduce_sum((double)(acc0 + acc1));
    if (t == 0) pairp[blockIdx.x * 25 + blockIdx.y] = v;
}

// ---------------------------------------------------------------------------
// k_final: reduce 625 pair partials + 64 negpen partials, emit scalar.
// ---------------------------------------------------------------------------
__global__ __launch_bounds__(256) void k_final(const double* __restrict__ pairp,
                                               const double* __restrict__ negp,
                                               float* __restrict__ out) {
    int t = threadIdx.x;
    double s = 0.0;
    for (int i = t; i < 625; i += 256) s += pairp[i];
    double ps = block_reduce_sum(s);
    double n = (t < 64) ? negp[t] : 0.0;
    double ns = block_reduce_sum(n);
    if (t == 0) {
        double mean_pair = ps / 40960000.0;                    // 6400*6400
        float losses = fmaxf((float)mean_pair + 5.25f, 0.0f);  // + 3.5*1.5
        float neg = (float)(ns / 196608.0);
        out[0] = losses + neg;
    }
}

// ---------------- launch ----------------

extern "C" void kernel_launch(void* const* d_in, const int* in_sizes, int n_in,
                              void* d_out, int out_size, void* d_ws, size_t ws_size,
                              hipStream_t stream) {
    const float* pred = (const float*)d_in[0];   // [64,3,32,32,5]
    const float* tgt  = (const float*)d_in[1];   // [64,100,4]
    float* out = (float*)d_out;

    char* ws = (char*)d_ws;
    double* negp  = (double*)ws;             // 64 doubles
    double* sl1p  = negp + 64;               // 25 (padded to 32)
    double* pairp = negp + 96;               // 625 doubles -> ends at 721*8 = 5768
    float* fbase  = (float*)(ws + 6400);     // 16B-aligned float region
    float* predc  = fbase;                   // 25600 floats
    float* targc  = fbase + 25600;           // 25600
    float* confv  = fbase + 51200;           // 6400
    float* diouv  = fbase + 57600;           // 6400
    unsigned int* maxiou_bits = (unsigned int*)(fbase + 64000);  // 6400

    k_topk<<<64, 256, 0, stream>>>(pred, tgt, predc, targc, confv, maxiou_bits, negp);
    k_maxiou<<<dim3(25, 32), 256, 0, stream>>>(predc, targc, maxiou_bits, diouv, sl1p);
    k_pair<<<dim3(25, 25), 256, 0, stream>>>(maxiou_bits, diouv, confv, sl1p, pairp);
    k_final<<<1, 256, 0, stream>>>(pairp, negp, out);
}